// Round 2
// baseline (1168.153 us; speedup 1.0000x reference)
//
#include <hip/hip_runtime.h>
#include <cstdint>

// ---------------- problem constants ----------------
#define NB     2
#define SEQ    2048
#define DIMN   2048
#define NROWS  (NB*SEQ)        // 4096
#define NHEADS 32
#define DHEAD  64
#define FFN    8192
#define HC     10368           // used cols of h: 2048 q | 64 k | 64 v | 8192 ffn
#define WINLD  18560           // W_in full leading dim (cols 10368..18560 unused by ref)
#define OI     10240           // W_out rows (attn 2048 | ffn 8192)

typedef __bf16 bf16_t;
typedef bf16_t bf16x8 __attribute__((ext_vector_type(8)));
typedef bf16_t bf16x4 __attribute__((ext_vector_type(4)));
typedef bf16_t bf16x2 __attribute__((ext_vector_type(2)));
typedef float  f32x4  __attribute__((ext_vector_type(4)));

typedef const uint32_t __attribute__((address_space(1)))* as1p;
typedef uint32_t __attribute__((address_space(3)))* as3p;

// async global->LDS, 16B/lane. LDS dest = wave-uniform base + lane*16 (guide §5).
__device__ __forceinline__ void load_lds16(const void* g, void* l) {
  __builtin_amdgcn_global_load_lds(
      reinterpret_cast<as1p>(reinterpret_cast<uintptr_t>(g)),
      reinterpret_cast<as3p>(reinterpret_cast<uintptr_t>(l)),
      16, 0, 0);
}

// ---------------- 1. LayerNorm -> bf16 ----------------
__global__ __launch_bounds__(256) void ln_kernel(const float* __restrict__ x,
                                                 const float* __restrict__ gamma,
                                                 const float* __restrict__ beta,
                                                 bf16_t* __restrict__ xnb)
{
  const int row = blockIdx.x;
  const int t = threadIdx.x;
  const float4* xr = (const float4*)(x + (size_t)row * DIMN);
  float4 v0 = xr[t], v1 = xr[t + 256];
  float s  = v0.x+v0.y+v0.z+v0.w + v1.x+v1.y+v1.z+v1.w;
  float ss = v0.x*v0.x+v0.y*v0.y+v0.z*v0.z+v0.w*v0.w
           + v1.x*v1.x+v1.y*v1.y+v1.z*v1.z+v1.w*v1.w;
#pragma unroll
  for (int off = 32; off; off >>= 1) { s += __shfl_xor(s, off); ss += __shfl_xor(ss, off); }
  __shared__ float red[8];
  const int w = t >> 6;
  if ((t & 63) == 0) { red[w] = s; red[w + 4] = ss; }
  __syncthreads();
  s  = red[0]+red[1]+red[2]+red[3];
  ss = red[4]+red[5]+red[6]+red[7];
  const float mu   = s * (1.f/DIMN);
  const float var  = ss * (1.f/DIMN) - mu*mu;
  const float rstd = rsqrtf(var + 1e-5f);
  const float4* g4 = (const float4*)gamma;
  const float4* b4 = (const float4*)beta;
  float4 ga0 = g4[t], ga1 = g4[t+256], be0 = b4[t], be1 = b4[t+256];
  float4 y0, y1;
  y0.x = (v0.x-mu)*rstd*ga0.x + be0.x;  y0.y = (v0.y-mu)*rstd*ga0.y + be0.y;
  y0.z = (v0.z-mu)*rstd*ga0.z + be0.z;  y0.w = (v0.w-mu)*rstd*ga0.w + be0.w;
  y1.x = (v1.x-mu)*rstd*ga1.x + be1.x;  y1.y = (v1.y-mu)*rstd*ga1.y + be1.y;
  y1.z = (v1.z-mu)*rstd*ga1.z + be1.z;  y1.w = (v1.w-mu)*rstd*ga1.w + be1.w;
  bf16_t* xo = xnb + (size_t)row * DIMN;
  bf16x4 o0 = {(bf16_t)y0.x, (bf16_t)y0.y, (bf16_t)y0.z, (bf16_t)y0.w};
  bf16x4 o1 = {(bf16_t)y1.x, (bf16_t)y1.y, (bf16_t)y1.z, (bf16_t)y1.w};
  *(bf16x4*)(xo + t*4)        = o0;
  *(bf16x4*)(xo + (t+256)*4)  = o1;
}

// ---------------- 2. transpose-cast fp32 -> bf16 (out[r][c] = in[c][r]) ----------------
// 128 in-rows x 32 in-cols per block; bf16x2 stores (256B/wave write segments)
__global__ __launch_bounds__(256) void tcast_kernel(const float* __restrict__ in, int ld_in,
                                                    bf16_t* __restrict__ out, int out_cols)
{
  __shared__ float tile[128][33];
  const int t = threadIdx.x;
  const int ic0 = blockIdx.x * 32;    // in col block = out row block
  const int ir0 = blockIdx.y * 128;   // in row block = out col block
#pragma unroll
  for (int k = 0; k < 16; k++) {
    const int idx = k*256 + t, row = idx >> 5, col = idx & 31;
    tile[row][col] = in[(size_t)(ir0 + row) * ld_in + ic0 + col];
  }
  __syncthreads();
#pragma unroll
  for (int k = 0; k < 8; k++) {
    const int idx = k*256 + t, r = idx >> 6, cp = idx & 63;
    bf16x2 v = {(bf16_t)tile[cp*2][r], (bf16_t)tile[cp*2 + 1][r]};
    *(bf16x2*)&out[(size_t)(ic0 + r) * out_cols + ir0 + cp*2] = v;
  }
}

// ---------------- 3. GEMM1: h = xn @ W_in  (m97 structure, Bt = W_in^T) ----------------
// C[4096][HC] bf16 <- A[4096][2048] bf16 * Bt[HC][2048] bf16
// 1-D grid 2592; chunk swizzle: 9 chunks x (9 n-tiles x 32 m-tiles, m-fastest)
// so co-resident blocks share a small set of B-tiles (L2/LLC locality).
__global__ __launch_bounds__(256, 2) void gemm1_kernel(const bf16_t* __restrict__ A,
                                                       const bf16_t* __restrict__ Bt,
                                                       bf16_t* __restrict__ C)
{
  __shared__ __align__(16) bf16_t As[128*32];
  __shared__ __align__(16) bf16_t Bs[128*32];
  const int t = threadIdx.x;
  const int id = blockIdx.x;
  const int chunk = id / 288;
  const int rem = id - chunk * 288;
  const int m0 = (rem & 31) << 7;
  const int n0 = (chunk * 9 + (rem >> 5)) << 7;
  const int l = t & 63, w = t >> 6;
  const int wm = (w >> 1) << 6, wn = (w & 1) << 6;
  const int lr = l & 15, lq = l >> 4;

  f32x4 acc[4][4];
  const f32x4 z4 = {0.f, 0.f, 0.f, 0.f};
#pragma unroll
  for (int i = 0; i < 4; i++)
#pragma unroll
    for (int j = 0; j < 4; j++) acc[i][j] = z4;

  const int srow = t >> 2, scol = (t & 3) << 3;
  bf16_t* aW = As + ((t & 192) << 3);   // wave-uniform LDS base (w*512 elems)
  bf16_t* bW = Bs + ((t & 192) << 3);
  const bf16_t* ag = A  + (size_t)(m0 + srow) * DIMN + scol;
  const bf16_t* bg = Bt + (size_t)(n0 + srow) * DIMN + scol;

  for (int k0 = 0; k0 < DIMN; k0 += 32) {
    load_lds16(ag + k0,                   aW);
    load_lds16(ag + k0 + (size_t)64*DIMN, aW + 2048);
    load_lds16(bg + k0,                   bW);
    load_lds16(bg + k0 + (size_t)64*DIMN, bW + 2048);
    __syncthreads();
    bf16x8 af[4], bb[4];
#pragma unroll
    for (int mt = 0; mt < 4; mt++)
      af[mt] = *(const bf16x8*)&As[(wm + mt*16 + lr)*32 + lq*8];
#pragma unroll
    for (int nt = 0; nt < 4; nt++)
      bb[nt] = *(const bf16x8*)&Bs[(wn + nt*16 + lr)*32 + lq*8];
#pragma unroll
    for (int mt = 0; mt < 4; mt++)
#pragma unroll
      for (int nt = 0; nt < 4; nt++)
        acc[mt][nt] = __builtin_amdgcn_mfma_f32_16x16x32_bf16(af[mt], bb[nt], acc[mt][nt], 0, 0, 0);
    __syncthreads();
  }
  // C/D layout: col = lane&15, row = (lane>>4)*4 + r (m89-verified)
#pragma unroll
  for (int mt = 0; mt < 4; mt++)
#pragma unroll
    for (int nt = 0; nt < 4; nt++) {
      const int rrow = m0 + wm + mt*16 + lq*4;
      const int ccol = n0 + wn + nt*16 + lr;
      bf16_t* cp = C + (size_t)rrow * HC + ccol;
#pragma unroll
      for (int r = 0; r < 4; r++)
        cp[(size_t)r * HC] = (bf16_t)acc[mt][nt][r];
    }
}

// ---------------- 4. RoPE in-place on q,k of h; extract V^T ----------------
__global__ __launch_bounds__(256) void rope_kernel(bf16_t* __restrict__ H, bf16_t* __restrict__ Vt)
{
  const int row = blockIdx.x;          // b*SEQ + s
  const int s = row & (SEQ - 1);
  const int b = row >> 11;
  bf16_t* hr = H + (size_t)row * HC;
  const int t = threadIdx.x;
  for (int task = t; task < 1056; task += 256) {
    const int hd = task >> 5, j = task & 31;
    const int base = (hd < 32) ? hd*64 : 2048;
    const float inv = exp2f(-(float)j * 0.41524101186092437f);
    const float ang = (float)s * inv;
    float sn, cs;
    sincosf(ang, &sn, &cs);
    const float x1 = (float)hr[base + j], x2 = (float)hr[base + j + 32];
    const float sc = (hd < 32) ? 0.125f : 1.0f;   // SCALE on q only
    hr[base + j]      = (bf16_t)((x1*cs - x2*sn) * sc);
    hr[base + j + 32] = (bf16_t)((x2*cs + x1*sn) * sc);
  }
  for (int d = t; d < 64; d += 256)
    Vt[(size_t)(b*64 + d) * SEQ + s] = hr[2112 + d];
}

// ---------------- 5. flash attention (causal, MQA) ----------------
// grid (SEQ/64, NHEADS, NB); BQ=64 (16 rows/wave), BKV=128, D=64
__global__ __launch_bounds__(256, 2) void attn_kernel(const bf16_t* __restrict__ H,
                                                      const bf16_t* __restrict__ Vt,
                                                      bf16_t* __restrict__ AttnOut)
{
  __shared__ __align__(16) bf16_t Qs[64*72];
  __shared__ __align__(16) bf16_t Ks[128*72];
  __shared__ __align__(16) bf16_t Vts[64*136];
  __shared__ __align__(16) bf16_t Ps[64*136];
  const int t = threadIdx.x, l = t & 63, w = t >> 6, lr = l & 15, lq = l >> 4;
  const int qb = blockIdx.x, head = blockIdx.y, b = blockIdx.z;
  const int q0 = qb * 64;
  const size_t hbase = (size_t)(b * SEQ) * HC;

#pragma unroll
  for (int i = 0; i < 2; i++) {   // stage Q tile (rotated+scaled q from h)
    const int id = t + i*256, row = id >> 3, ch = (id & 7) << 3;
    bf16x8 v = *(const bf16x8*)&H[hbase + (size_t)(q0 + row) * HC + head*64 + ch];
    *(bf16x8*)&Qs[row*72 + ch] = v;
  }
  f32x4 accO[4];
  const f32x4 z4 = {0.f,0.f,0.f,0.f};
#pragma unroll
  for (int i = 0; i < 4; i++) accO[i] = z4;
  float m_run[4], l_run[4];
#pragma unroll
  for (int r = 0; r < 4; r++) { m_run[r] = -3.0e38f; l_run[r] = 0.f; }
  const int ntiles = (qb >> 1) + 1;   // j0 <= q0 (multiples of 128)
  __syncthreads();

  for (int tile = 0; tile < ntiles; tile++) {
    const int j0 = tile * 128;
    // live-column count in this KV tile: ntmax in {4 (diagonal, even qb), 8}
    const int ntmax = ((q0 + 63 - j0) >> 4) >= 7 ? 8 : 4;
#pragma unroll
    for (int i = 0; i < 4; i++) {   // stage K tile
      const int id = t + i*256, row = id >> 3, ch = (id & 7) << 3;
      bf16x8 v = *(const bf16x8*)&H[hbase + (size_t)(j0 + row) * HC + 2048 + ch];
      *(bf16x8*)&Ks[row*72 + ch] = v;
    }
#pragma unroll
    for (int i = 0; i < 4; i++) {   // stage V^T tile
      const int id = t + i*256, row = id >> 4, ch = (id & 15) << 3;
      bf16x8 v = *(const bf16x8*)&Vt[(size_t)(b*64 + row) * SEQ + j0 + ch];
      *(bf16x8*)&Vts[row*136 + ch] = v;
    }
    __syncthreads();

    // S = Q K^T : wave w owns q-rows [w*16, w*16+16)
    f32x4 accS[8];
#pragma unroll
    for (int i = 0; i < 8; i++) accS[i] = z4;
    bf16x8 aq[2];
#pragma unroll
    for (int kt = 0; kt < 2; kt++)
      aq[kt] = *(const bf16x8*)&Qs[(w*16 + lr)*72 + kt*32 + lq*8];
    for (int nt = 0; nt < ntmax; nt++)
#pragma unroll
      for (int kt = 0; kt < 2; kt++) {
        bf16x8 bk = *(const bf16x8*)&Ks[(nt*16 + lr)*72 + kt*32 + lq*8];
        accS[nt] = __builtin_amdgcn_mfma_f32_16x16x32_bf16(aq[kt], bk, accS[nt], 0, 0, 0);
      }
    // causal mask (wave-uniform skip when whole tile is below diagonal)
    const int rg0 = q0 + w*16 + lq*4;
    if (j0 + 127 > q0 + w*16) {
      for (int nt = 0; nt < ntmax; nt++) {
        const int cg = j0 + nt*16 + lr;
#pragma unroll
        for (int r = 0; r < 4; r++)
          if (cg > rg0 + r) accS[nt][r] = -3.0e38f;
      }
    }
    // online softmax (rows partitioned per-wave; reduce over low-4 lane bits)
    float al[4];
#pragma unroll
    for (int r = 0; r < 4; r++) {
      float m = accS[0][r];
      for (int nt = 1; nt < ntmax; nt++) m = fmaxf(m, accS[nt][r]);
      m = fmaxf(m, __shfl_xor(m, 1)); m = fmaxf(m, __shfl_xor(m, 2));
      m = fmaxf(m, __shfl_xor(m, 4)); m = fmaxf(m, __shfl_xor(m, 8));
      const float nm = fmaxf(m_run[r], m);
      al[r] = __expf(m_run[r] - nm);
      m_run[r] = nm;
    }
    for (int nt = 0; nt < ntmax; nt++)
#pragma unroll
      for (int r = 0; r < 4; r++)
        accS[nt][r] = __expf(accS[nt][r] - m_run[r]);
#pragma unroll
    for (int r = 0; r < 4; r++) {
      float sum = 0.f;
      for (int nt = 0; nt < ntmax; nt++) sum += accS[nt][r];
      sum += __shfl_xor(sum, 1); sum += __shfl_xor(sum, 2);
      sum += __shfl_xor(sum, 4); sum += __shfl_xor(sum, 8);
      l_run[r] = l_run[r]*al[r] + sum;
    }
#pragma unroll
    for (int nt = 0; nt < 4; nt++)
#pragma unroll
      for (int r = 0; r < 4; r++) accO[nt][r] *= al[r];
    // P: C-layout regs -> LDS (A-operand layout for PV) — m120-verified transform
    for (int nt = 0; nt < ntmax; nt++)
#pragma unroll
      for (int r = 0; r < 4; r++)
        Ps[(w*16 + lq*4 + r)*136 + nt*16 + lr] = (bf16_t)accS[nt][r];
    __syncthreads();
    // O += P V  (only live k-range: kt < ntmax/2)
    for (int kt = 0; kt < (ntmax >> 1); kt++) {
      bf16x8 ap = *(const bf16x8*)&Ps[(w*16 + lr)*136 + kt*32 + lq*8];
#pragma unroll
      for (int nt = 0; nt < 4; nt++) {
        bf16x8 bv = *(const bf16x8*)&Vts[(nt*16 + lr)*136 + kt*32 + lq*8];
        accO[nt] = __builtin_amdgcn_mfma_f32_16x16x32_bf16(ap, bv, accO[nt], 0, 0, 0);
      }
    }
    __syncthreads();   // protect Ks/Vts before next tile's restage
  }
  float inv_l[4];
#pragma unroll
  for (int r = 0; r < 4; r++) inv_l[r] = 1.f / l_run[r];
#pragma unroll
  for (int nt = 0; nt < 4; nt++)
#pragma unroll
    for (int r = 0; r < 4; r++)
      AttnOut[(size_t)(b*SEQ + q0 + w*16 + lq*4 + r) * DIMN + head*64 + nt*16 + lr]
          = (bf16_t)(accO[nt][r] * inv_l[r]);
}

// ---------------- 6. GEMM2: out = [attn|ffn] @ W_out + xn ----------------
// 1-D grid 512 (all co-resident); XCD-pair swizzle: same-n blocks progress
// through K in lockstep with B k-slices hot in their XCD's L2.
__global__ __launch_bounds__(256, 2) void gemm2_kernel(const bf16_t* __restrict__ Attn,
                                                       const bf16_t* __restrict__ H,
                                                       const bf16_t* __restrict__ Bt,
                                                       const bf16_t* __restrict__ Res,
                                                       float* __restrict__ Out)
{
  __shared__ __align__(16) bf16_t As[128*32];
  __shared__ __align__(16) bf16_t Bs[128*32];
  const int t = threadIdx.x;
  const int id = blockIdx.x;
  const int n0 = ((((id & 7) << 1) | ((id >> 3) & 1))) << 7;
  const int m0 = (id >> 4) << 7;
  const int l = t & 63, w = t >> 6;
  const int wm = (w >> 1) << 6, wn = (w & 1) << 6;
  const int lr = l & 15, lq = l >> 4;

  f32x4 acc[4][4];
  const f32x4 z4 = {0.f, 0.f, 0.f, 0.f};
#pragma unroll
  for (int i = 0; i < 4; i++)
#pragma unroll
    for (int j = 0; j < 4; j++) acc[i][j] = z4;

  const int srow = t >> 2, scol = (t & 3) << 3;
  bf16_t* aW = As + ((t & 192) << 3);
  bf16_t* bW = Bs + ((t & 192) << 3);
  const bf16_t* agA = Attn + (size_t)(m0 + srow) * DIMN + scol;
  const bf16_t* agH = H    + (size_t)(m0 + srow) * HC + 2176 + scol;
  const bf16_t* bg  = Bt   + (size_t)(n0 + srow) * OI + scol;

  for (int k0 = 0; k0 < OI; k0 += 32) {
    const bf16_t* ag; size_t rstep;
    if (k0 < DIMN) { ag = agA + k0;          rstep = (size_t)64 * DIMN; }
    else           { ag = agH + (k0 - DIMN); rstep = (size_t)64 * HC; }
    load_lds16(ag,         aW);
    load_lds16(ag + rstep, aW + 2048);
    load_lds16(bg + k0,                 bW);
    load_lds16(bg + k0 + (size_t)64*OI, bW + 2048);
    __syncthreads();
    bf16x8 af[4], bb[4];
#pragma unroll
    for (int mt = 0; mt < 4; mt++)
      af[mt] = *(const bf16x8*)&As[(wm + mt*16 + lr)*32 + lq*8];
#pragma unroll
    for (int nt = 0; nt < 4; nt++)
      bb[nt] = *(const bf16x8*)&Bs[(wn + nt*16 + lr)*32 + lq*8];
#pragma unroll
    for (int mt = 0; mt < 4; mt++)
#pragma unroll
      for (int nt = 0; nt < 4; nt++)
        acc[mt][nt] = __builtin_amdgcn_mfma_f32_16x16x32_bf16(af[mt], bb[nt], acc[mt][nt], 0, 0, 0);
    __syncthreads();
  }
#pragma unroll
  for (int mt = 0; mt < 4; mt++)
#pragma unroll
    for (int nt = 0; nt < 4; nt++) {
      const int rrow = m0 + wm + mt*16 + lq*4;
      const int ccol = n0 + wn + nt*16 + lr;
#pragma unroll
      for (int r = 0; r < 4; r++) {
        const size_t idx = (size_t)(rrow + r) * DIMN + ccol;
        Out[idx] = acc[mt][nt][r] + (float)Res[idx];
      }
    }
}

// ---------------- launcher ----------------
extern "C" void kernel_launch(void* const* d_in, const int* in_sizes, int n_in,
                              void* d_out, int out_size, void* d_ws, size_t ws_size,
                              hipStream_t stream)
{
  const float* x     = (const float*)d_in[0];
  const float* W_in  = (const float*)d_in[1];
  const float* W_out = (const float*)d_in[2];
  const float* gamma = (const float*)d_in[3];
  const float* beta  = (const float*)d_in[4];
  float* out = (float*)d_out;

  char* ws = (char*)d_ws;
  bf16_t* xnb   = (bf16_t*)(ws);                 // 16,777,216
  bf16_t* h     = (bf16_t*)(ws + 16777216);      // 84,934,656
  bf16_t* WinT  = (bf16_t*)(ws + 101711872);     // 42,467,328  [HC][DIMN]
  bf16_t* WoutT = (bf16_t*)(ws + 144179200);     // 41,943,040  [DIMN][OI]
  bf16_t* Vt    = (bf16_t*)(ws + 186122240);     //    524,288  [NB][64][SEQ]
  bf16_t* attn  = (bf16_t*)(ws + 186646528);     // 16,777,216  [NROWS][DIMN]

  ln_kernel<<<NROWS, 256, 0, stream>>>(x, gamma, beta, xnb);
  tcast_kernel<<<dim3(HC/32, DIMN/128), 256, 0, stream>>>(W_in, WINLD, WinT, DIMN);
  tcast_kernel<<<dim3(DIMN/32, OI/128), 256, 0, stream>>>(W_out, DIMN, WoutT, OI);
  gemm1_kernel<<<2592, 256, 0, stream>>>(xnb, WinT, h);
  rope_kernel<<<NROWS, 256, 0, stream>>>(h, Vt);
  attn_kernel<<<dim3(SEQ/64, NHEADS, NB), 256, 0, stream>>>(h, Vt, attn);
  gemm2_kernel<<<512, 256, 0, stream>>>(attn, h, WoutT, xnb, out);
}

// Round 3
// 912.117 us; speedup vs baseline: 1.2807x; 1.2807x over previous
//
#include <hip/hip_runtime.h>
#include <cstdint>

// ---------------- problem constants ----------------
#define NB     2
#define SEQ    2048
#define DIMN   2048
#define NROWS  (NB*SEQ)        // 4096
#define NHEADS 32
#define DHEAD  64
#define FFN    8192
#define HC     10368           // used cols of h: 2048 q | 64 k | 64 v | 8192 ffn
#define WINLD  18560           // W_in full leading dim (cols 10368..18560 unused by ref)
#define OI     10240           // W_out rows (attn 2048 | ffn 8192)

typedef __bf16 bf16_t;
typedef bf16_t bf16x8 __attribute__((ext_vector_type(8)));
typedef bf16_t bf16x4 __attribute__((ext_vector_type(4)));
typedef bf16_t bf16x2 __attribute__((ext_vector_type(2)));
typedef float  f32x4  __attribute__((ext_vector_type(4)));

typedef const uint32_t __attribute__((address_space(1)))* as1p;
typedef uint32_t __attribute__((address_space(3)))* as3p;

// async global->LDS, 16B/lane. LDS dest = wave-uniform base + lane*16 (guide §5).
__device__ __forceinline__ void load_lds16(const void* g, void* l) {
  __builtin_amdgcn_global_load_lds(
      reinterpret_cast<as1p>(reinterpret_cast<uintptr_t>(g)),
      reinterpret_cast<as3p>(reinterpret_cast<uintptr_t>(l)),
      16, 0, 0);
}

// ---------------- 1. LayerNorm -> bf16 ----------------
__global__ __launch_bounds__(256) void ln_kernel(const float* __restrict__ x,
                                                 const float* __restrict__ gamma,
                                                 const float* __restrict__ beta,
                                                 bf16_t* __restrict__ xnb)
{
  const int row = blockIdx.x;
  const int t = threadIdx.x;
  const float4* xr = (const float4*)(x + (size_t)row * DIMN);
  float4 v0 = xr[t], v1 = xr[t + 256];
  float s  = v0.x+v0.y+v0.z+v0.w + v1.x+v1.y+v1.z+v1.w;
  float ss = v0.x*v0.x+v0.y*v0.y+v0.z*v0.z+v0.w*v0.w
           + v1.x*v1.x+v1.y*v1.y+v1.z*v1.z+v1.w*v1.w;
#pragma unroll
  for (int off = 32; off; off >>= 1) { s += __shfl_xor(s, off); ss += __shfl_xor(ss, off); }
  __shared__ float red[8];
  const int w = t >> 6;
  if ((t & 63) == 0) { red[w] = s; red[w + 4] = ss; }
  __syncthreads();
  s  = red[0]+red[1]+red[2]+red[3];
  ss = red[4]+red[5]+red[6]+red[7];
  const float mu   = s * (1.f/DIMN);
  const float var  = ss * (1.f/DIMN) - mu*mu;
  const float rstd = rsqrtf(var + 1e-5f);
  const float4* g4 = (const float4*)gamma;
  const float4* b4 = (const float4*)beta;
  float4 ga0 = g4[t], ga1 = g4[t+256], be0 = b4[t], be1 = b4[t+256];
  float4 y0, y1;
  y0.x = (v0.x-mu)*rstd*ga0.x + be0.x;  y0.y = (v0.y-mu)*rstd*ga0.y + be0.y;
  y0.z = (v0.z-mu)*rstd*ga0.z + be0.z;  y0.w = (v0.w-mu)*rstd*ga0.w + be0.w;
  y1.x = (v1.x-mu)*rstd*ga1.x + be1.x;  y1.y = (v1.y-mu)*rstd*ga1.y + be1.y;
  y1.z = (v1.z-mu)*rstd*ga1.z + be1.z;  y1.w = (v1.w-mu)*rstd*ga1.w + be1.w;
  bf16_t* xo = xnb + (size_t)row * DIMN;
  bf16x4 o0 = {(bf16_t)y0.x, (bf16_t)y0.y, (bf16_t)y0.z, (bf16_t)y0.w};
  bf16x4 o1 = {(bf16_t)y1.x, (bf16_t)y1.y, (bf16_t)y1.z, (bf16_t)y1.w};
  *(bf16x4*)(xo + t*4)        = o0;
  *(bf16x4*)(xo + (t+256)*4)  = o1;
}

// ---------------- 2. transpose-cast fp32 -> bf16 (out[r][c] = in[c][r]) ----------------
// 128 in-rows x 32 in-cols per block; bf16x2 stores (256B/wave write segments)
__global__ __launch_bounds__(256) void tcast_kernel(const float* __restrict__ in, int ld_in,
                                                    bf16_t* __restrict__ out, int out_cols)
{
  __shared__ float tile[128][33];
  const int t = threadIdx.x;
  const int ic0 = blockIdx.x * 32;    // in col block = out row block
  const int ir0 = blockIdx.y * 128;   // in row block = out col block
#pragma unroll
  for (int k = 0; k < 16; k++) {
    const int idx = k*256 + t, row = idx >> 5, col = idx & 31;
    tile[row][col] = in[(size_t)(ir0 + row) * ld_in + ic0 + col];
  }
  __syncthreads();
#pragma unroll
  for (int k = 0; k < 8; k++) {
    const int idx = k*256 + t, r = idx >> 6, cp = idx & 63;
    bf16x2 v = {(bf16_t)tile[cp*2][r], (bf16_t)tile[cp*2 + 1][r]};
    *(bf16x2*)&out[(size_t)(ic0 + r) * out_cols + ir0 + cp*2] = v;
  }
}

// ---------------- 3. GEMM1: h = xn @ W_in  (m97 structure, Bt = W_in^T) ----------------
// 1-D grid 2592; chunk swizzle: 9 chunks x (9 n-tiles x 32 m-tiles, m-fastest)
__global__ __launch_bounds__(256, 2) void gemm1_kernel(const bf16_t* __restrict__ A,
                                                       const bf16_t* __restrict__ Bt,
                                                       bf16_t* __restrict__ C)
{
  __shared__ __align__(16) bf16_t As[128*32];
  __shared__ __align__(16) bf16_t Bs[128*32];
  const int t = threadIdx.x;
  const int id = blockIdx.x;
  const int chunk = id / 288;
  const int rem = id - chunk * 288;
  const int m0 = (rem & 31) << 7;
  const int n0 = (chunk * 9 + (rem >> 5)) << 7;
  const int l = t & 63, w = t >> 6;
  const int wm = (w >> 1) << 6, wn = (w & 1) << 6;
  const int lr = l & 15, lq = l >> 4;

  f32x4 acc[4][4];
  const f32x4 z4 = {0.f, 0.f, 0.f, 0.f};
#pragma unroll
  for (int i = 0; i < 4; i++)
#pragma unroll
    for (int j = 0; j < 4; j++) acc[i][j] = z4;

  const int srow = t >> 2, scol = (t & 3) << 3;
  bf16_t* aW = As + ((t & 192) << 3);   // wave-uniform LDS base
  bf16_t* bW = Bs + ((t & 192) << 3);
  const bf16_t* ag = A  + (size_t)(m0 + srow) * DIMN + scol;
  const bf16_t* bg = Bt + (size_t)(n0 + srow) * DIMN + scol;

  for (int k0 = 0; k0 < DIMN; k0 += 32) {
    load_lds16(ag + k0,                   aW);
    load_lds16(ag + k0 + (size_t)64*DIMN, aW + 2048);
    load_lds16(bg + k0,                   bW);
    load_lds16(bg + k0 + (size_t)64*DIMN, bW + 2048);
    __syncthreads();
    bf16x8 af[4], bb[4];
#pragma unroll
    for (int mt = 0; mt < 4; mt++)
      af[mt] = *(const bf16x8*)&As[(wm + mt*16 + lr)*32 + lq*8];
#pragma unroll
    for (int nt = 0; nt < 4; nt++)
      bb[nt] = *(const bf16x8*)&Bs[(wn + nt*16 + lr)*32 + lq*8];
#pragma unroll
    for (int mt = 0; mt < 4; mt++)
#pragma unroll
      for (int nt = 0; nt < 4; nt++)
        acc[mt][nt] = __builtin_amdgcn_mfma_f32_16x16x32_bf16(af[mt], bb[nt], acc[mt][nt], 0, 0, 0);
    __syncthreads();
  }
#pragma unroll
  for (int mt = 0; mt < 4; mt++)
#pragma unroll
    for (int nt = 0; nt < 4; nt++) {
      const int rrow = m0 + wm + mt*16 + lq*4;
      const int ccol = n0 + wn + nt*16 + lr;
      bf16_t* cp = C + (size_t)rrow * HC + ccol;
#pragma unroll
      for (int r = 0; r < 4; r++)
        cp[(size_t)r * HC] = (bf16_t)acc[mt][nt][r];
    }
}

// ---------------- 4. RoPE in-place on q,k of h; extract V^T ----------------
__global__ __launch_bounds__(256) void rope_kernel(bf16_t* __restrict__ H, bf16_t* __restrict__ Vt)
{
  const int row = blockIdx.x;          // b*SEQ + s
  const int s = row & (SEQ - 1);
  const int b = row >> 11;
  bf16_t* hr = H + (size_t)row * HC;
  const int t = threadIdx.x;
  for (int task = t; task < 1056; task += 256) {
    const int hd = task >> 5, j = task & 31;
    const int base = (hd < 32) ? hd*64 : 2048;
    const float inv = exp2f(-(float)j * 0.41524101186092437f);
    const float ang = (float)s * inv;
    float sn, cs;
    sincosf(ang, &sn, &cs);
    const float x1 = (float)hr[base + j], x2 = (float)hr[base + j + 32];
    const float sc = (hd < 32) ? 0.125f : 1.0f;   // SCALE on q only
    hr[base + j]      = (bf16_t)((x1*cs - x2*sn) * sc);
    hr[base + j + 32] = (bf16_t)((x2*cs + x1*sn) * sc);
  }
  for (int d = t; d < 64; d += 256)
    Vt[(size_t)(b*64 + d) * SEQ + s] = hr[2112 + d];
}

// ---------------- 5. flash attention (causal, MQA) ----------------
// Tile body templated on compile-time NTMAX so all loops fully unroll and
// accS stays in registers (runtime bound in R2 caused scratch spill, 2x slowdown).
template<int NTMAX, bool MASK>
__device__ __forceinline__ void attn_tile_body(
    const bf16_t* __restrict__ Qs, const bf16_t* __restrict__ Ks,
    const bf16_t* __restrict__ Vts, bf16_t* __restrict__ Ps,
    f32x4 (&accO)[4], float (&m_run)[4], float (&l_run)[4],
    int w, int lr, int lq, int q0, int j0)
{
  const f32x4 z4 = {0.f,0.f,0.f,0.f};
  f32x4 accS[NTMAX];
#pragma unroll
  for (int i = 0; i < NTMAX; i++) accS[i] = z4;
  bf16x8 aq[2];
#pragma unroll
  for (int kt = 0; kt < 2; kt++)
    aq[kt] = *(const bf16x8*)&Qs[(w*16 + lr)*72 + kt*32 + lq*8];
#pragma unroll
  for (int nt = 0; nt < NTMAX; nt++)
#pragma unroll
    for (int kt = 0; kt < 2; kt++) {
      bf16x8 bk = *(const bf16x8*)&Ks[(nt*16 + lr)*72 + kt*32 + lq*8];
      accS[nt] = __builtin_amdgcn_mfma_f32_16x16x32_bf16(aq[kt], bk, accS[nt], 0, 0, 0);
    }
  if (MASK) {
    const int rg0 = q0 + w*16 + lq*4;
#pragma unroll
    for (int nt = 0; nt < NTMAX; nt++) {
      const int cg = j0 + nt*16 + lr;
#pragma unroll
      for (int r = 0; r < 4; r++)
        if (cg > rg0 + r) accS[nt][r] = -3.0e38f;
    }
  }
  float al[4];
#pragma unroll
  for (int r = 0; r < 4; r++) {
    float m = accS[0][r];
#pragma unroll
    for (int nt = 1; nt < NTMAX; nt++) m = fmaxf(m, accS[nt][r]);
    m = fmaxf(m, __shfl_xor(m, 1)); m = fmaxf(m, __shfl_xor(m, 2));
    m = fmaxf(m, __shfl_xor(m, 4)); m = fmaxf(m, __shfl_xor(m, 8));
    const float nm = fmaxf(m_run[r], m);
    al[r] = __expf(m_run[r] - nm);
    m_run[r] = nm;
  }
#pragma unroll
  for (int nt = 0; nt < NTMAX; nt++)
#pragma unroll
    for (int r = 0; r < 4; r++)
      accS[nt][r] = __expf(accS[nt][r] - m_run[r]);
#pragma unroll
  for (int r = 0; r < 4; r++) {
    float sum = 0.f;
#pragma unroll
    for (int nt = 0; nt < NTMAX; nt++) sum += accS[nt][r];
    sum += __shfl_xor(sum, 1); sum += __shfl_xor(sum, 2);
    sum += __shfl_xor(sum, 4); sum += __shfl_xor(sum, 8);
    l_run[r] = l_run[r]*al[r] + sum;
  }
#pragma unroll
  for (int nt = 0; nt < 4; nt++)
#pragma unroll
    for (int r = 0; r < 4; r++) accO[nt][r] *= al[r];
  // P: C-layout regs -> LDS (A-operand layout for PV) — m120-verified transform
#pragma unroll
  for (int nt = 0; nt < NTMAX; nt++)
#pragma unroll
    for (int r = 0; r < 4; r++)
      Ps[(w*16 + lq*4 + r)*136 + nt*16 + lr] = (bf16_t)accS[nt][r];
  __syncthreads();   // block-uniform call site
  // O += P V (only live k-range)
#pragma unroll
  for (int kt = 0; kt < NTMAX/2; kt++) {
    bf16x8 ap = *(const bf16x8*)&Ps[(w*16 + lr)*136 + kt*32 + lq*8];
#pragma unroll
    for (int nt = 0; nt < 4; nt++) {
      bf16x8 bv = *(const bf16x8*)&Vts[(nt*16 + lr)*136 + kt*32 + lq*8];
      accO[nt] = __builtin_amdgcn_mfma_f32_16x16x32_bf16(ap, bv, accO[nt], 0, 0, 0);
    }
  }
}

// grid (SEQ/64, NHEADS, NB); BQ=64 (16 rows/wave), BKV=128, D=64
__global__ __launch_bounds__(256, 2) void attn_kernel(const bf16_t* __restrict__ H,
                                                      const bf16_t* __restrict__ Vt,
                                                      bf16_t* __restrict__ AttnOut)
{
  __shared__ __align__(16) bf16_t Qs[64*72];
  __shared__ __align__(16) bf16_t Ks[128*72];
  __shared__ __align__(16) bf16_t Vts[64*136];
  __shared__ __align__(16) bf16_t Ps[64*136];
  const int t = threadIdx.x, l = t & 63, w = t >> 6, lr = l & 15, lq = l >> 4;
  const int qb = blockIdx.x, head = blockIdx.y, b = blockIdx.z;
  const int q0 = qb * 64;
  const size_t hbase = (size_t)(b * SEQ) * HC;

#pragma unroll
  for (int i = 0; i < 2; i++) {   // stage Q tile (rotated+scaled q from h)
    const int id = t + i*256, row = id >> 3, ch = (id & 7) << 3;
    bf16x8 v = *(const bf16x8*)&H[hbase + (size_t)(q0 + row) * HC + head*64 + ch];
    *(bf16x8*)&Qs[row*72 + ch] = v;
  }
  f32x4 accO[4];
  const f32x4 z4 = {0.f,0.f,0.f,0.f};
#pragma unroll
  for (int i = 0; i < 4; i++) accO[i] = z4;
  float m_run[4], l_run[4];
#pragma unroll
  for (int r = 0; r < 4; r++) { m_run[r] = -3.0e38f; l_run[r] = 0.f; }
  const int ntiles = (qb >> 1) + 1;   // j0 <= q0 (multiples of 128)
  __syncthreads();

  for (int tile = 0; tile < ntiles; tile++) {
    const int j0 = tile * 128;
#pragma unroll
    for (int i = 0; i < 4; i++) {   // stage K tile
      const int id = t + i*256, row = id >> 3, ch = (id & 7) << 3;
      bf16x8 v = *(const bf16x8*)&H[hbase + (size_t)(j0 + row) * HC + 2048 + ch];
      *(bf16x8*)&Ks[row*72 + ch] = v;
    }
#pragma unroll
    for (int i = 0; i < 4; i++) {   // stage V^T tile
      const int id = t + i*256, row = id >> 4, ch = (id & 15) << 3;
      bf16x8 v = *(const bf16x8*)&Vt[(size_t)(b*64 + row) * SEQ + j0 + ch];
      *(bf16x8*)&Vts[row*136 + ch] = v;
    }
    __syncthreads();
    // block-uniform branch -> exactly one instantiation runs per tile
    if (tile < ntiles - 1)
      attn_tile_body<8,false>(Qs, Ks, Vts, Ps, accO, m_run, l_run, w, lr, lq, q0, j0);
    else if ((qb & 1) == 0)
      attn_tile_body<4,true >(Qs, Ks, Vts, Ps, accO, m_run, l_run, w, lr, lq, q0, j0);
    else
      attn_tile_body<8,true >(Qs, Ks, Vts, Ps, accO, m_run, l_run, w, lr, lq, q0, j0);
    __syncthreads();   // protect Ks/Vts before next tile's restage
  }
  float inv_l[4];
#pragma unroll
  for (int r = 0; r < 4; r++) inv_l[r] = 1.f / l_run[r];
#pragma unroll
  for (int nt = 0; nt < 4; nt++)
#pragma unroll
    for (int r = 0; r < 4; r++)
      AttnOut[(size_t)(b*SEQ + q0 + w*16 + lq*4 + r) * DIMN + head*64 + nt*16 + lr]
          = (bf16_t)(accO[nt][r] * inv_l[r]);
}

// ---------------- 6. GEMM2: out = [attn|ffn] @ W_out + xn ----------------
__global__ __launch_bounds__(256, 2) void gemm2_kernel(const bf16_t* __restrict__ Attn,
                                                       const bf16_t* __restrict__ H,
                                                       const bf16_t* __restrict__ Bt,
                                                       const bf16_t* __restrict__ Res,
                                                       float* __restrict__ Out)
{
  __shared__ __align__(16) bf16_t As[128*32];
  __shared__ __align__(16) bf16_t Bs[128*32];
  const int t = threadIdx.x;
  const int id = blockIdx.x;
  const int n0 = ((((id & 7) << 1) | ((id >> 3) & 1))) << 7;
  const int m0 = (id >> 4) << 7;
  const int l = t & 63, w = t >> 6;
  const int wm = (w >> 1) << 6, wn = (w & 1) << 6;
  const int lr = l & 15, lq = l >> 4;

  f32x4 acc[4][4];
  const f32x4 z4 = {0.f, 0.f, 0.f, 0.f};
#pragma unroll
  for (int i = 0; i < 4; i++)
#pragma unroll
    for (int j = 0; j < 4; j++) acc[i][j] = z4;

  const int srow = t >> 2, scol = (t & 3) << 3;
  bf16_t* aW = As + ((t & 192) << 3);
  bf16_t* bW = Bs + ((t & 192) << 3);
  const bf16_t* agA = Attn + (size_t)(m0 + srow) * DIMN + scol;
  const bf16_t* agH = H    + (size_t)(m0 + srow) * HC + 2176 + scol;
  const bf16_t* bg  = Bt   + (size_t)(n0 + srow) * OI + scol;

  for (int k0 = 0; k0 < OI; k0 += 32) {
    const bf16_t* ag; size_t rstep;
    if (k0 < DIMN) { ag = agA + k0;          rstep = (size_t)64 * DIMN; }
    else           { ag = agH + (k0 - DIMN); rstep = (size_t)64 * HC; }
    load_lds16(ag,         aW);
    load_lds16(ag + rstep, aW + 2048);
    load_lds16(bg + k0,                 bW);
    load_lds16(bg + k0 + (size_t)64*OI, bW + 2048);
    __syncthreads();
    bf16x8 af[4], bb[4];
#pragma unroll
    for (int mt = 0; mt < 4; mt++)
      af[mt] = *(const bf16x8*)&As[(wm + mt*16 + lr)*32 + lq*8];
#pragma unroll
    for (int nt = 0; nt < 4; nt++)
      bb[nt] = *(const bf16x8*)&Bs[(wn + nt*16 + lr)*32 + lq*8];
#pragma unroll
    for (int mt = 0; mt < 4; mt++)
#pragma unroll
      for (int nt = 0; nt < 4; nt++)
        acc[mt][nt] = __builtin_amdgcn_mfma_f32_16x16x32_bf16(af[mt], bb[nt], acc[mt][nt], 0, 0, 0);
    __syncthreads();
  }
#pragma unroll
  for (int mt = 0; mt < 4; mt++)
#pragma unroll
    for (int nt = 0; nt < 4; nt++) {
      const int rrow = m0 + wm + mt*16 + lq*4;
      const int ccol = n0 + wn + nt*16 + lr;
#pragma unroll
      for (int r = 0; r < 4; r++) {
        const size_t idx = (size_t)(rrow + r) * DIMN + ccol;
        Out[idx] = acc[mt][nt][r] + (float)Res[idx];
      }
    }
}

// ---------------- launcher ----------------
extern "C" void kernel_launch(void* const* d_in, const int* in_sizes, int n_in,
                              void* d_out, int out_size, void* d_ws, size_t ws_size,
                              hipStream_t stream)
{
  const float* x     = (const float*)d_in[0];
  const float* W_in  = (const float*)d_in[1];
  const float* W_out = (const float*)d_in[2];
  const float* gamma = (const float*)d_in[3];
  const float* beta  = (const float*)d_in[4];
  float* out = (float*)d_out;

  char* ws = (char*)d_ws;
  bf16_t* xnb   = (bf16_t*)(ws);                 // 16,777,216
  bf16_t* h     = (bf16_t*)(ws + 16777216);      // 84,934,656
  bf16_t* WinT  = (bf16_t*)(ws + 101711872);     // 42,467,328  [HC][DIMN]
  bf16_t* WoutT = (bf16_t*)(ws + 144179200);     // 41,943,040  [DIMN][OI]
  bf16_t* Vt    = (bf16_t*)(ws + 186122240);     //    524,288  [NB][64][SEQ]
  bf16_t* attn  = (bf16_t*)(ws + 186646528);     // 16,777,216  [NROWS][DIMN]

  ln_kernel<<<NROWS, 256, 0, stream>>>(x, gamma, beta, xnb);
  tcast_kernel<<<dim3(HC/32, DIMN/128), 256, 0, stream>>>(W_in, WINLD, WinT, DIMN);
  tcast_kernel<<<dim3(DIMN/32, OI/128), 256, 0, stream>>>(W_out, DIMN, WoutT, OI);
  gemm1_kernel<<<2592, 256, 0, stream>>>(xnb, WinT, h);
  rope_kernel<<<NROWS, 256, 0, stream>>>(h, Vt);
  attn_kernel<<<dim3(SEQ/64, NHEADS, NB), 256, 0, stream>>>(h, Vt, attn);
  gemm2_kernel<<<512, 256, 0, stream>>>(attn, h, WoutT, xnb, out);
}